// Round 1
// baseline (830.177 us; speedup 1.0000x reference)
//
#include <hip/hip_runtime.h>

typedef short short8 __attribute__((ext_vector_type(8)));
typedef float f32x4 __attribute__((ext_vector_type(4)));

#define MFMA_BF16 __builtin_amdgcn_mfma_f32_16x16x32_bf16

__device__ __forceinline__ unsigned short f2bf(float f) {
  unsigned int u = __float_as_uint(f);
  u += 0x7fffu + ((u >> 16) & 1u);   // round-to-nearest-even
  return (unsigned short)(u >> 16);
}

// ---------------------------------------------------------------------------
// GEMM: C[m,n] = sum_k A[m,k] * W[n,k] + bias[n]
// A: (M,K) f32 row-major, W: (N,K) f32 row-major, C: (M,N) f32.
// 128x128 tile, BK=32, 256 threads (4 waves), 16x16x32 bf16 MFMA.
// LDS layout per tile: [quad][m][8] with per-quad stride QS (pad 8 elems)
// so fragment ds_read_b128 is bank-conflict-free (2-way max).
// ---------------------------------------------------------------------------
#define QS 1032

__global__ __launch_bounds__(256) void gemm_xwt(
    const float* __restrict__ A, const float* __restrict__ W,
    const float* __restrict__ bias, float* __restrict__ C,
    int M, int N, int K) {
  __shared__ unsigned short As[4 * QS];
  __shared__ unsigned short Bs[4 * QS];
  const int t = threadIdx.x;
  const int lane = t & 63;
  const int w = t >> 6;
  const int wr = w >> 1, wc = w & 1;
  const int quad = lane >> 4, l16 = lane & 15;
  const int bm = blockIdx.y * 128, bn = blockIdx.x * 128;

  const f32x4 fzero = {0.f, 0.f, 0.f, 0.f};
  f32x4 acc[4][4];
  for (int i = 0; i < 4; ++i)
    for (int j = 0; j < 4; ++j) acc[i][j] = fzero;

  const int rowS = t >> 3;          // 0..31 (tile row per staging iter)
  const int f = t & 7;              // float4 index within 32-k row
  const int sq = f >> 1;            // LDS quad
  const int sh = (f & 1) * 4;       // element offset within quad-row

  for (int k0 = 0; k0 < K; k0 += 32) {
    __syncthreads();
    for (int r = 0; r < 4; ++r) {
      int m = r * 32 + rowS;
      float4 av = *(const float4*)&A[(size_t)(bm + m) * K + k0 + f * 4];
      float4 bv = *(const float4*)&W[(size_t)(bn + m) * K + k0 + f * 4];
      short4 a4, b4;
      a4.x = (short)f2bf(av.x); a4.y = (short)f2bf(av.y);
      a4.z = (short)f2bf(av.z); a4.w = (short)f2bf(av.w);
      b4.x = (short)f2bf(bv.x); b4.y = (short)f2bf(bv.y);
      b4.z = (short)f2bf(bv.z); b4.w = (short)f2bf(bv.w);
      *(short4*)&As[sq * QS + m * 8 + sh] = a4;
      *(short4*)&Bs[sq * QS + m * 8 + sh] = b4;
    }
    __syncthreads();
    short8 af[4], bfr[4];
    for (int mt = 0; mt < 4; ++mt)
      af[mt] = *(const short8*)&As[quad * QS + (wr * 64 + mt * 16 + l16) * 8];
    for (int nt = 0; nt < 4; ++nt)
      bfr[nt] = *(const short8*)&Bs[quad * QS + (wc * 64 + nt * 16 + l16) * 8];
    for (int mt = 0; mt < 4; ++mt)
      for (int nt = 0; nt < 4; ++nt)
        acc[mt][nt] = MFMA_BF16(af[mt], bfr[nt], acc[mt][nt], 0, 0, 0);
  }

  for (int mt = 0; mt < 4; ++mt)
    for (int nt = 0; nt < 4; ++nt) {
      int row = bm + wr * 64 + mt * 16 + quad * 4;
      int col = bn + wc * 64 + nt * 16 + l16;
      float bcol = bias[col];
      for (int r = 0; r < 4; ++r)
        C[(size_t)(row + r) * N + col] = acc[mt][nt][r] + bcol;
    }
}

// ---------------------------------------------------------------------------
// RMSNorm + rotary on Q,K; bf16 repack of Q,K,V into (b,h,l,d).
// One wave per (b,h,l) row of d=128; lane i handles dims i and i+64
// (the rotary pair). Softmax scale (1/sqrt(d)) * log2(e) folded into Q.
// ---------------------------------------------------------------------------
__global__ __launch_bounds__(256) void rmsrope(
    const float* __restrict__ Qf, const float* __restrict__ Kf,
    const float* __restrict__ Vf, const float* __restrict__ cosT,
    const float* __restrict__ sinT, unsigned short* __restrict__ Qb,
    unsigned short* __restrict__ Kb, unsigned short* __restrict__ Vb) {
  const int rid = blockIdx.x * 4 + (threadIdx.x >> 6);  // (b*16+h)*1024 + l
  const int lane = threadIdx.x & 63;
  const int li = rid & 1023;
  const int bh = rid >> 10;
  const int hi = bh & 15, bi = bh >> 4;
  const int src = (bi * 1024 + li) * 2048 + hi * 128;
  const int dst = rid * 128;
  const float c = cosT[li * 64 + lane];
  const float s = sinT[li * 64 + lane];

  float q1 = Qf[src + lane], q2 = Qf[src + 64 + lane];
  float ss = q1 * q1 + q2 * q2;
  for (int off = 32; off; off >>= 1) ss += __shfl_xor(ss, off, 64);
  float r = rsqrtf(ss * (1.f / 128.f) + 1e-6f);
  float qa = q1 * r, qb2 = q2 * r;
  const float qsc = 0.08838834764831845f * 1.4426950408889634f; // 1/sqrt(128)*log2e
  Qb[dst + lane]      = f2bf((qa * c - qb2 * s) * qsc);
  Qb[dst + 64 + lane] = f2bf((qa * s + qb2 * c) * qsc);

  float k1 = Kf[src + lane], k2 = Kf[src + 64 + lane];
  float ks = k1 * k1 + k2 * k2;
  for (int off = 32; off; off >>= 1) ks += __shfl_xor(ks, off, 64);
  float rk = rsqrtf(ks * (1.f / 128.f) + 1e-6f);
  float ka = k1 * rk, kb2 = k2 * rk;
  Kb[dst + lane]      = f2bf(ka * c - kb2 * s);
  Kb[dst + 64 + lane] = f2bf(ka * s + kb2 * c);

  float v1 = Vf[src + lane], v2 = Vf[src + 64 + lane];
  Vb[dst + lane]      = f2bf(v1);
  Vb[dst + 64 + lane] = f2bf(v2);
}

// ---------------------------------------------------------------------------
// Flash attention, causal. Block = 4 waves; wave handles 16 q-rows; block
// covers 64 q-rows of one (b,h). s-tiles of 32. QK^T and PV via MFMA.
// S in C-layout -> online softmax (quad-local shuffles) -> P through LDS
// (A-layout) -> PV with V transposed in LDS. O scaled by 1/L at the end.
// Scores already in log2 units (scale folded into Q) -> exp2f.
// ---------------------------------------------------------------------------
__global__ __launch_bounds__(256) void attn(
    const unsigned short* __restrict__ Qb, const unsigned short* __restrict__ Kb,
    const unsigned short* __restrict__ Vb, float* __restrict__ Of) {
  __shared__ unsigned short Kl[32 * 136];   // K-tile (s,d), stride 136
  __shared__ unsigned short Vt[128 * 40];   // V-tile transposed (d,s), stride 40
  __shared__ unsigned short Pl[4][16 * 40]; // per-wave P tile, stride 40
  const int t = threadIdx.x, lane = t & 63, w = t >> 6;
  const int quad = lane >> 4, l16 = lane & 15;
  const int bh = blockIdx.y;
  const int q0 = blockIdx.x * 64;
  const unsigned short* Qh = Qb + (size_t)bh * 1024 * 128;
  const unsigned short* Kh = Kb + (size_t)bh * 1024 * 128;
  const unsigned short* Vh = Vb + (size_t)bh * 1024 * 128;

  short8 aQ[4];
  {
    int qr = q0 + w * 16 + l16;
    for (int kk = 0; kk < 4; ++kk)
      aQ[kk] = *(const short8*)&Qh[(size_t)qr * 128 + kk * 32 + quad * 8];
  }

  const f32x4 fzero = {0.f, 0.f, 0.f, 0.f};
  f32x4 oacc[8];
  for (int i = 0; i < 8; ++i) oacc[i] = fzero;
  float Mr[4], Lr[4];
  for (int r = 0; r < 4; ++r) { Mr[r] = -1e30f; Lr[r] = 0.f; }

  const int myq = q0 + w * 16 + quad * 4;       // + r
  const int wave_qmax = q0 + w * 16 + 15;
  const int nT = (q0 >> 5) + 2;

  const int srow = t >> 4;          // 0..15
  const int c8 = (t & 15) * 8;      // d-offset (8 elems = 16B)

  for (int st = 0; st < nT; ++st) {
    const int s0 = st * 32;
    __syncthreads();
    for (int it = 0; it < 2; ++it) {
      int rr = srow + it * 16;
      int4 kv = *(const int4*)&Kh[(size_t)(s0 + rr) * 128 + c8];
      *(int4*)&Kl[rr * 136 + c8] = kv;
      int4 vv = *(const int4*)&Vh[(size_t)(s0 + rr) * 128 + c8];
      union { int4 v; unsigned short u[8]; } uu;
      uu.v = vv;
      for (int j = 0; j < 8; ++j) Vt[(c8 + j) * 40 + rr] = uu.u[j];
    }
    __syncthreads();
    if (s0 > wave_qmax) continue;   // fully-masked tile for this wave

    f32x4 s_acc0 = fzero, s_acc1 = fzero;
    for (int kk = 0; kk < 4; ++kk) {
      short8 b0 = *(const short8*)&Kl[l16 * 136 + kk * 32 + quad * 8];
      short8 b1 = *(const short8*)&Kl[(16 + l16) * 136 + kk * 32 + quad * 8];
      s_acc0 = MFMA_BF16(aQ[kk], b0, s_acc0, 0, 0, 0);
      s_acc1 = MFMA_BF16(aQ[kk], b1, s_acc1, 0, 0, 0);
    }

    float al[4];
    for (int r = 0; r < 4; ++r) {
      const int qr = myq + r;
      float sv0 = s_acc0[r]; if (s0 + l16 > qr)      sv0 = -1e30f;
      float sv1 = s_acc1[r]; if (s0 + 16 + l16 > qr) sv1 = -1e30f;
      float mx = fmaxf(sv0, sv1);
      mx = fmaxf(mx, __shfl_xor(mx, 1, 64));
      mx = fmaxf(mx, __shfl_xor(mx, 2, 64));
      mx = fmaxf(mx, __shfl_xor(mx, 4, 64));
      mx = fmaxf(mx, __shfl_xor(mx, 8, 64));
      float nm = fmaxf(Mr[r], mx);
      al[r] = exp2f(Mr[r] - nm);
      Mr[r] = nm;
      float p0 = exp2f(sv0 - nm);
      float p1 = exp2f(sv1 - nm);
      float rsum = p0 + p1;
      rsum += __shfl_xor(rsum, 1, 64);
      rsum += __shfl_xor(rsum, 2, 64);
      rsum += __shfl_xor(rsum, 4, 64);
      rsum += __shfl_xor(rsum, 8, 64);
      Lr[r] = Lr[r] * al[r] + rsum;
      Pl[w][(quad * 4 + r) * 40 + l16]      = f2bf(p0);
      Pl[w][(quad * 4 + r) * 40 + 16 + l16] = f2bf(p1);
    }
    for (int nt = 0; nt < 8; ++nt)
      for (int r = 0; r < 4; ++r) oacc[nt][r] *= al[r];

    short8 aP = *(const short8*)&Pl[w][l16 * 40 + quad * 8];
    for (int nt = 0; nt < 8; ++nt) {
      short8 bV = *(const short8*)&Vt[(nt * 16 + l16) * 40 + quad * 8];
      oacc[nt] = MFMA_BF16(aP, bV, oacc[nt], 0, 0, 0);
    }
  }

  for (int r = 0; r < 4; ++r) {
    float inv = 1.f / Lr[r];
    size_t row = (size_t)(bh * 1024 + myq + r) * 128;
    for (int nt = 0; nt < 8; ++nt)
      Of[row + nt * 16 + l16] = oacc[nt][r] * inv;
  }
}

// ---------------------------------------------------------------------------
// v-projection removal: o' = o - (o . vhat) vhat, vhat = v / max(||v||, eps).
// Reads O (b,h,l,d) f32 + V f32 (b,l,e); writes O' (b,l,e) f32 for final GEMM.
// ---------------------------------------------------------------------------
__global__ __launch_bounds__(256) void vnfix(
    const float* __restrict__ Of, const float* __restrict__ Vf,
    float* __restrict__ Op) {
  const int rid = blockIdx.x * 4 + (threadIdx.x >> 6);
  const int lane = threadIdx.x & 63;
  const int li = rid & 1023;
  const int bh = rid >> 10;
  const int hi = bh & 15, bi = bh >> 4;
  const int src = (bi * 1024 + li) * 2048 + hi * 128;
  float o1 = Of[rid * 128 + lane], o2 = Of[rid * 128 + 64 + lane];
  float v1 = Vf[src + lane], v2 = Vf[src + 64 + lane];
  float vv = v1 * v1 + v2 * v2;
  float dd = o1 * v1 + o2 * v2;
  for (int off = 32; off; off >>= 1) {
    vv += __shfl_xor(vv, off, 64);
    dd += __shfl_xor(dd, off, 64);
  }
  float vn = fmaxf(sqrtf(vv), 1e-9f);
  float tc = dd / (vn * vn);
  Op[src + lane]      = o1 - tc * v1;
  Op[src + 64 + lane] = o2 - tc * v2;
}

// ---------------------------------------------------------------------------
// b=4, l=1024, e=2048, h=16, d=128. Workspace map (bytes):
//   Qf f32 (b*l,e):   0        .. 32M    (later aliased by Of (b,h,l,d))
//   Kf f32 (b*l,e):   32M      .. 64M    (later aliased by Op (b,l,e))
//   Vf f32 (b*l,e):   64M      .. 96M    (live until vnfix)
//   Qb bf16 (b,h,l,d) 96M  Kb 112M  Vb 128M .. 144M  -> ~151MB total
// ---------------------------------------------------------------------------
extern "C" void kernel_launch(void* const* d_in, const int* in_sizes, int n_in,
                              void* d_out, int out_size, void* d_ws, size_t ws_size,
                              hipStream_t stream) {
  const float* query = (const float*)d_in[0];
  const float* key   = (const float*)d_in[1];
  const float* value = (const float*)d_in[2];
  const float* cosT  = (const float*)d_in[4];
  const float* sinT  = (const float*)d_in[5];
  const float* Wq = (const float*)d_in[6];
  const float* bq = (const float*)d_in[7];
  const float* Wk = (const float*)d_in[8];
  const float* bk = (const float*)d_in[9];
  const float* Wv = (const float*)d_in[10];
  const float* bv = (const float*)d_in[11];
  const float* Wo = (const float*)d_in[12];
  const float* bo = (const float*)d_in[13];
  float* out = (float*)d_out;

  char* ws = (char*)d_ws;
  const size_t SZF = 33554432;  // 4096*2048*4
  const size_t SZB = 16777216;  // 4096*2048*2
  float* Qf = (float*)(ws);
  float* Kf = (float*)(ws + SZF);
  float* Vf = (float*)(ws + 2 * SZF);
  unsigned short* Qb = (unsigned short*)(ws + 3 * SZF);
  unsigned short* Kb = (unsigned short*)(ws + 3 * SZF + SZB);
  unsigned short* Vb = (unsigned short*)(ws + 3 * SZF + 2 * SZB);
  float* Of = Qf;  // alias: Qf dead after rmsrope
  float* Op = Kf;  // alias: Kf dead after rmsrope

  dim3 gg(16, 32);  // N/128, M/128
  gemm_xwt<<<gg, 256, 0, stream>>>(query, Wq, bq, Qf, 4096, 2048, 2048);
  gemm_xwt<<<gg, 256, 0, stream>>>(key,   Wk, bk, Kf, 4096, 2048, 2048);
  gemm_xwt<<<gg, 256, 0, stream>>>(value, Wv, bv, Vf, 4096, 2048, 2048);
  rmsrope<<<16384, 256, 0, stream>>>(Qf, Kf, Vf, cosT, sinT, Qb, Kb, Vb);
  attn<<<dim3(16, 64), 256, 0, stream>>>(Qb, Kb, Vb, Of);
  vnfix<<<16384, 256, 0, stream>>>(Of, Vf, Op);
  gemm_xwt<<<gg, 256, 0, stream>>>(Op, Wo, bo, out, 4096, 2048, 2048);
}

// Round 2
// 541.202 us; speedup vs baseline: 1.5339x; 1.5339x over previous
//
#include <hip/hip_runtime.h>

typedef short short8 __attribute__((ext_vector_type(8)));
typedef float f32x4 __attribute__((ext_vector_type(4)));

#define MFMA_BF16 __builtin_amdgcn_mfma_f32_16x16x32_bf16

__device__ __forceinline__ unsigned short f2bf(float f) {
  unsigned int u = __float_as_uint(f);
  u += 0x7fffu + ((u >> 16) & 1u);   // round-to-nearest-even
  return (unsigned short)(u >> 16);
}
__device__ __forceinline__ float bf2f(unsigned short u) {
  return __uint_as_float(((unsigned int)u) << 16);
}

// async global->LDS, 16B per lane. LDS dest = wave-uniform base + lane*16.
typedef __attribute__((address_space(1))) const unsigned int as1_u32;
typedef __attribute__((address_space(3))) unsigned int as3_u32;
__device__ __forceinline__ void gld16(const void* g, void* l) {
  __builtin_amdgcn_global_load_lds((as1_u32*)(unsigned long long)g,
                                   (as3_u32*)(unsigned int)(unsigned long long)l,
                                   16, 0, 0);
}

// ---------------------------------------------------------------------------
// f32 -> bf16 convert (8 elems/thread)
// ---------------------------------------------------------------------------
__global__ __launch_bounds__(256) void cvtbf(const float* __restrict__ src,
                                             unsigned short* __restrict__ dst,
                                             int n8) {
  int i = blockIdx.x * 256 + threadIdx.x;
  if (i >= n8) return;
  const float4* s4 = (const float4*)src;
  float4 a = s4[2 * i], b = s4[2 * i + 1];
  short8 o = {(short)f2bf(a.x), (short)f2bf(a.y), (short)f2bf(a.z), (short)f2bf(a.w),
              (short)f2bf(b.x), (short)f2bf(b.y), (short)f2bf(b.z), (short)f2bf(b.w)};
  *(short8*)&dst[(size_t)i * 8] = o;
}

// ---------------------------------------------------------------------------
// GEMM (m97 structure): C[m,n] = sum_k A[m,k]*W[n,k] + bias[n]
// A (M,K) bf16, W (N,K) bf16. 128x128 tile, BK=32, 256 thr, global_load_lds.
// LDS: plain [m][k0..31] bf16, no padding (required by lane-order DMA).
// OUTBF: write bf16, else f32.
// ---------------------------------------------------------------------------
template <bool OUTBF>
__global__ __launch_bounds__(256) void gemm_bf16(
    const unsigned short* __restrict__ A, const unsigned short* __restrict__ W,
    const float* __restrict__ bias, float* __restrict__ Cf,
    unsigned short* __restrict__ Cb, int M, int N, int K) {
  __shared__ unsigned short As[128 * 32];
  __shared__ unsigned short Bs[128 * 32];
  const int t = threadIdx.x, lane = t & 63, w = t >> 6;
  const int wr = w >> 1, wc = w & 1;
  const int quad = lane >> 4, l16 = lane & 15;
  const int bm = blockIdx.y * 128, bn = blockIdx.x * 128;

  // staging: wave w, instr j covers rows (w*2+j)*16 + (lane>>2), kchunk lane&3
  const int r0 = (w * 2 + 0) * 16 + (lane >> 2);
  const int r1 = (w * 2 + 1) * 16 + (lane >> 2);
  const size_t a0 = (size_t)(bm + r0) * K + (lane & 3) * 8;
  const size_t a1 = (size_t)(bm + r1) * K + (lane & 3) * 8;
  const size_t b0 = (size_t)(bn + r0) * K + (lane & 3) * 8;
  const size_t b1 = (size_t)(bn + r1) * K + (lane & 3) * 8;
  unsigned short* lA0 = &As[(w * 2 + 0) * 512];
  unsigned short* lA1 = &As[(w * 2 + 1) * 512];
  unsigned short* lB0 = &Bs[(w * 2 + 0) * 512];
  unsigned short* lB1 = &Bs[(w * 2 + 1) * 512];

  const f32x4 fz = {0.f, 0.f, 0.f, 0.f};
  f32x4 acc[4][4];
  for (int i = 0; i < 4; ++i)
    for (int j = 0; j < 4; ++j) acc[i][j] = fz;

  for (int k0 = 0; k0 < K; k0 += 32) {
    __syncthreads();
    gld16(A + a0 + k0, lA0);
    gld16(A + a1 + k0, lA1);
    gld16(W + b0 + k0, lB0);
    gld16(W + b1 + k0, lB1);
    __syncthreads();
    short8 af[4], bfv[4];
    for (int mt = 0; mt < 4; ++mt)
      af[mt] = *(const short8*)&As[(wr * 64 + mt * 16 + l16) * 32 + quad * 8];
    for (int nt = 0; nt < 4; ++nt)
      bfv[nt] = *(const short8*)&Bs[(wc * 64 + nt * 16 + l16) * 32 + quad * 8];
    for (int mt = 0; mt < 4; ++mt)
      for (int nt = 0; nt < 4; ++nt)
        acc[mt][nt] = MFMA_BF16(af[mt], bfv[nt], acc[mt][nt], 0, 0, 0);
  }

  for (int mt = 0; mt < 4; ++mt)
    for (int nt = 0; nt < 4; ++nt) {
      int row = bm + wr * 64 + mt * 16 + quad * 4;
      int col = bn + wc * 64 + nt * 16 + l16;
      float bc = bias[col];
      for (int r = 0; r < 4; ++r) {
        float v = acc[mt][nt][r] + bc;
        if (OUTBF) Cb[(size_t)(row + r) * N + col] = f2bf(v);
        else       Cf[(size_t)(row + r) * N + col] = v;
      }
    }
}

// ---------------------------------------------------------------------------
// RMSNorm + rotary on Q,K (bf16 in, bf16 out, f32 math). Wave per row.
// Softmax scale (1/sqrt(d)) * log2(e) folded into Q.
// ---------------------------------------------------------------------------
__global__ __launch_bounds__(256) void rmsrope(
    const unsigned short* __restrict__ Qf, const unsigned short* __restrict__ Kf,
    const float* __restrict__ cosT, const float* __restrict__ sinT,
    unsigned short* __restrict__ Qb, unsigned short* __restrict__ Kb) {
  const int rid = blockIdx.x * 4 + (threadIdx.x >> 6);  // (b*16+h)*1024 + l
  const int lane = threadIdx.x & 63;
  const int li = rid & 1023;
  const int bh = rid >> 10;
  const int hi = bh & 15, bi = bh >> 4;
  const int src = (bi * 1024 + li) * 2048 + hi * 128;
  const int dst = rid * 128;
  const float c = cosT[li * 64 + lane];
  const float s = sinT[li * 64 + lane];

  float q1 = bf2f(Qf[src + lane]), q2 = bf2f(Qf[src + 64 + lane]);
  float ss = q1 * q1 + q2 * q2;
  for (int off = 32; off; off >>= 1) ss += __shfl_xor(ss, off, 64);
  float r = rsqrtf(ss * (1.f / 128.f) + 1e-6f);
  float qa = q1 * r, qb2 = q2 * r;
  const float qsc = 0.08838834764831845f * 1.4426950408889634f;
  Qb[dst + lane]      = f2bf((qa * c - qb2 * s) * qsc);
  Qb[dst + 64 + lane] = f2bf((qa * s + qb2 * c) * qsc);

  float k1 = bf2f(Kf[src + lane]), k2 = bf2f(Kf[src + 64 + lane]);
  float ks = k1 * k1 + k2 * k2;
  for (int off = 32; off; off >>= 1) ks += __shfl_xor(ks, off, 64);
  float rk = rsqrtf(ks * (1.f / 128.f) + 1e-6f);
  float ka = k1 * rk, kb2 = k2 * rk;
  Kb[dst + lane]      = f2bf(ka * c - kb2 * s);
  Kb[dst + 64 + lane] = f2bf(ka * s + kb2 * c);
}

// ---------------------------------------------------------------------------
// V transpose: Vf bf16 (b,l,e) -> Vt bf16 (b,h,d,l). Block per (bh, 64-l tile).
// ---------------------------------------------------------------------------
__global__ __launch_bounds__(256) void vtrans(
    const unsigned short* __restrict__ Vf, unsigned short* __restrict__ Vt) {
  __shared__ unsigned short Vsh[64 * 136];
  const int t = threadIdx.x;
  const int bh = blockIdx.y, l0 = blockIdx.x * 64;
  const int hi = bh & 15, bi = bh >> 4;
  // load 64 rows x 128 d (row-major), vector
  {
    int row = t >> 2, c4 = t & 3;
    const unsigned short* src = &Vf[(size_t)(bi * 1024 + l0 + row) * 2048 + hi * 128];
    for (int i = 0; i < 4; ++i) {
      int chunk = c4 * 4 + i;
      *(int4*)&Vsh[row * 136 + chunk * 8] = *(const int4*)&src[chunk * 8];
    }
  }
  __syncthreads();
  // write transposed: rows d (128), 64 l contiguous
  {
    int d = t >> 1, half = t & 1;
    unsigned short* dst = &Vt[(size_t)bh * 131072 + (size_t)d * 1024 + l0 + half * 32];
    for (int g = 0; g < 4; ++g) {
      short8 o;
      for (int j = 0; j < 8; ++j)
        o[j] = (short)Vsh[(half * 32 + g * 8 + j) * 136 + d];
      *(short8*)&dst[g * 8] = o;
    }
  }
}

// ---------------------------------------------------------------------------
// Flash attention, causal, static softmax max (scores bounded: |s*log2e|<=16.45).
// Block: 4 waves, q-tile 128 (wave owns 32 rows), s-tile 64.
// K staged (s,d) stride 136; V staged from pre-transposed global (d,s) stride 72.
// P round-trips LDS (C-layout -> A-layout). No online max, no rescale.
// Heavy q-blocks launched first.
// ---------------------------------------------------------------------------
__global__ __launch_bounds__(256) void attn(
    const unsigned short* __restrict__ Qb, const unsigned short* __restrict__ Kb,
    const unsigned short* __restrict__ Vt, float* __restrict__ Of) {
  __shared__ unsigned short Kl[64 * 136];
  __shared__ unsigned short Vl[128 * 72];
  __shared__ unsigned short Pl[4][32 * 72];
  const int t = threadIdx.x, lane = t & 63, w = t >> 6;
  const int quad = lane >> 4, l16 = lane & 15;
  const int bh = blockIdx.y;
  const int q0 = (7 - (int)blockIdx.x) * 128;
  const int nT = (q0 >> 6) + 2;
  const unsigned short* Qh = Qb + (size_t)bh * 131072;
  const unsigned short* Kh = Kb + (size_t)bh * 131072;
  const unsigned short* Vh = Vt + (size_t)bh * 131072;

  short8 aQ[2][4];
  for (int mi = 0; mi < 2; ++mi) {
    int qr = q0 + w * 32 + mi * 16 + l16;
    for (int kk = 0; kk < 4; ++kk)
      aQ[mi][kk] = *(const short8*)&Qh[(size_t)qr * 128 + kk * 32 + quad * 8];
  }

  const f32x4 fz = {0.f, 0.f, 0.f, 0.f};
  f32x4 oacc[2][8];
  for (int i = 0; i < 2; ++i)
    for (int j = 0; j < 8; ++j) oacc[i][j] = fz;
  float Lr[2][4] = {{0.f, 0.f, 0.f, 0.f}, {0.f, 0.f, 0.f, 0.f}};
  const int wqmax = q0 + w * 32 + 31;
  const int krow = t >> 4, kcol = (t & 15) * 8;
  const int vdr = t >> 3, vc = (t & 7) * 8;

  for (int st = 0; st < nT; ++st) {
    const int s0 = st * 64;
    __syncthreads();
    for (int p = 0; p < 4; ++p) {
      int r = p * 16 + krow;
      *(int4*)&Kl[r * 136 + kcol] = *(const int4*)&Kh[(size_t)(s0 + r) * 128 + kcol];
      int d = p * 32 + vdr;
      *(int4*)&Vl[d * 72 + vc] = *(const int4*)&Vh[(size_t)d * 1024 + s0 + vc];
    }
    __syncthreads();
    if (s0 > wqmax) continue;   // fully masked for this wave
    const bool diag = (st >= nT - 2);

    // QK^T
    f32x4 sfr[2][4];
    for (int i = 0; i < 2; ++i)
      for (int j = 0; j < 4; ++j) sfr[i][j] = fz;
    for (int kk = 0; kk < 4; ++kk)
      for (int ni = 0; ni < 4; ++ni) {
        short8 bK = *(const short8*)&Kl[(ni * 16 + l16) * 136 + kk * 32 + quad * 8];
        sfr[0][ni] = MFMA_BF16(aQ[0][kk], bK, sfr[0][ni], 0, 0, 0);
        sfr[1][ni] = MFMA_BF16(aQ[1][kk], bK, sfr[1][ni], 0, 0, 0);
      }

    // softmax (static max 16.5) + P store (bf16, A-layout source)
    for (int mi = 0; mi < 2; ++mi)
      for (int r = 0; r < 4; ++r) {
        int q = q0 + w * 32 + mi * 16 + quad * 4 + r;
        float ps = 0.f;
        for (int ni = 0; ni < 4; ++ni) {
          float sv = sfr[mi][ni][r];
          if (diag && (s0 + ni * 16 + l16 > q)) sv = -30000.f;
          float pp = exp2f(sv - 16.5f);
          ps += pp;
          Pl[w][(mi * 16 + quad * 4 + r) * 72 + ni * 16 + l16] = f2bf(pp);
        }
        ps += __shfl_xor(ps, 1, 64);
        ps += __shfl_xor(ps, 2, 64);
        ps += __shfl_xor(ps, 4, 64);
        ps += __shfl_xor(ps, 8, 64);
        Lr[mi][r] += ps;
      }

    // P @ V
    for (int kk = 0; kk < 2; ++kk) {
      short8 aP0 = *(const short8*)&Pl[w][(l16) * 72 + kk * 32 + quad * 8];
      short8 aP1 = *(const short8*)&Pl[w][(16 + l16) * 72 + kk * 32 + quad * 8];
      for (int nt = 0; nt < 8; ++nt) {
        short8 bV = *(const short8*)&Vl[(nt * 16 + l16) * 72 + kk * 32 + quad * 8];
        oacc[0][nt] = MFMA_BF16(aP0, bV, oacc[0][nt], 0, 0, 0);
        oacc[1][nt] = MFMA_BF16(aP1, bV, oacc[1][nt], 0, 0, 0);
      }
    }
  }

  for (int mi = 0; mi < 2; ++mi)
    for (int r = 0; r < 4; ++r) {
      int q = q0 + w * 32 + mi * 16 + quad * 4 + r;
      float inv = 1.f / Lr[mi][r];
      size_t base = ((size_t)bh * 1024 + q) * 128;
      for (int nt = 0; nt < 8; ++nt)
        Of[base + nt * 16 + l16] = oacc[mi][nt][r] * inv;
    }
}

// ---------------------------------------------------------------------------
// v-projection removal: o' = o - (o.v / max(|v|,eps)^2) v. Out bf16 (b,l,e).
// ---------------------------------------------------------------------------
__global__ __launch_bounds__(256) void vnfix(
    const float* __restrict__ Of, const unsigned short* __restrict__ Vf,
    unsigned short* __restrict__ Op) {
  const int rid = blockIdx.x * 4 + (threadIdx.x >> 6);
  const int lane = threadIdx.x & 63;
  const int li = rid & 1023;
  const int bh = rid >> 10;
  const int hi = bh & 15, bi = bh >> 4;
  const int src = (bi * 1024 + li) * 2048 + hi * 128;
  float o1 = Of[(size_t)rid * 128 + lane], o2 = Of[(size_t)rid * 128 + 64 + lane];
  float v1 = bf2f(Vf[src + lane]), v2 = bf2f(Vf[src + 64 + lane]);
  float vv = v1 * v1 + v2 * v2;
  float dd = o1 * v1 + o2 * v2;
  for (int off = 32; off; off >>= 1) {
    vv += __shfl_xor(vv, off, 64);
    dd += __shfl_xor(dd, off, 64);
  }
  float vn = fmaxf(sqrtf(vv), 1e-9f);
  float tc = dd / (vn * vn);
  Op[src + lane]      = f2bf(o1 - tc * v1);
  Op[src + 64 + lane] = f2bf(o2 - tc * v2);
}

// ---------------------------------------------------------------------------
// b=4, l=1024, e=2048, h=16, d=128. Workspace (128 MB):
//  0   Xq bf16 16M   -> Qb (b,h,l,d) after gemm1
//  16M Xk bf16 16M   -> Kb
//  32M Xv bf16 16M   -> Vt (b,h,d,l)
//  48M Wq 8M, 56M Wk 8M   -> Op bf16 (b,l,e) 16M
//  64M Wv 8M, 72M Wo 8M
//  80M Qf bf16 16M, 96M Kf bf16 16M  -> Of f32 (b,h,l,d) 32M
//  112M Vf bf16 16M
// ---------------------------------------------------------------------------
extern "C" void kernel_launch(void* const* d_in, const int* in_sizes, int n_in,
                              void* d_out, int out_size, void* d_ws, size_t ws_size,
                              hipStream_t stream) {
  const float* query = (const float*)d_in[0];
  const float* key   = (const float*)d_in[1];
  const float* value = (const float*)d_in[2];
  const float* cosT  = (const float*)d_in[4];
  const float* sinT  = (const float*)d_in[5];
  const float* Wq = (const float*)d_in[6];
  const float* bq = (const float*)d_in[7];
  const float* Wk = (const float*)d_in[8];
  const float* bk = (const float*)d_in[9];
  const float* Wv = (const float*)d_in[10];
  const float* bv = (const float*)d_in[11];
  const float* Wo = (const float*)d_in[12];
  const float* bo = (const float*)d_in[13];
  float* out = (float*)d_out;

  char* ws = (char*)d_ws;
  const size_t MB = 1048576;
  unsigned short* Xq  = (unsigned short*)(ws);
  unsigned short* Xk  = (unsigned short*)(ws + 16 * MB);
  unsigned short* Xv  = (unsigned short*)(ws + 32 * MB);
  unsigned short* Wqb = (unsigned short*)(ws + 48 * MB);
  unsigned short* Wkb = (unsigned short*)(ws + 56 * MB);
  unsigned short* Wvb = (unsigned short*)(ws + 64 * MB);
  unsigned short* Wob = (unsigned short*)(ws + 72 * MB);
  unsigned short* Qf  = (unsigned short*)(ws + 80 * MB);
  unsigned short* Kf  = (unsigned short*)(ws + 96 * MB);
  unsigned short* Vf  = (unsigned short*)(ws + 112 * MB);
  unsigned short* Qbb = Xq;                       // aliases (dead regions)
  unsigned short* Kbb = Xk;
  unsigned short* Vtb = Xv;
  float*          Ofp = (float*)(ws + 80 * MB);
  unsigned short* Opb = (unsigned short*)(ws + 48 * MB);

  // 1. convert inputs/weights to bf16
  cvtbf<<<4096, 256, 0, stream>>>(query, Xq, 1048576);
  cvtbf<<<4096, 256, 0, stream>>>(key,   Xk, 1048576);
  cvtbf<<<4096, 256, 0, stream>>>(value, Xv, 1048576);
  cvtbf<<<2048, 256, 0, stream>>>(Wq, Wqb, 524288);
  cvtbf<<<2048, 256, 0, stream>>>(Wk, Wkb, 524288);
  cvtbf<<<2048, 256, 0, stream>>>(Wv, Wvb, 524288);
  cvtbf<<<2048, 256, 0, stream>>>(Wo, Wob, 524288);

  // 2. projections (bf16 out)
  dim3 gg(16, 32);
  gemm_bf16<true><<<gg, 256, 0, stream>>>(Xq, Wqb, bq, nullptr, Qf, 4096, 2048, 2048);
  gemm_bf16<true><<<gg, 256, 0, stream>>>(Xk, Wkb, bk, nullptr, Kf, 4096, 2048, 2048);
  gemm_bf16<true><<<gg, 256, 0, stream>>>(Xv, Wvb, bv, nullptr, Vf, 4096, 2048, 2048);

  // 3. rmsnorm+rope, V transpose
  rmsrope<<<16384, 256, 0, stream>>>(Qf, Kf, cosT, sinT, Qbb, Kbb);
  vtrans<<<dim3(16, 64), 256, 0, stream>>>(Vf, Vtb);

  // 4. attention
  attn<<<dim3(8, 64), 256, 0, stream>>>(Qbb, Kbb, Vtb, Ofp);

  // 5. v-projection removal (bf16 out)
  vnfix<<<16384, 256, 0, stream>>>(Ofp, Vf, Opb);

  // 6. output projection (f32 out)
  gemm_bf16<false><<<gg, 256, 0, stream>>>(Opb, Wob, bo, out, nullptr, 4096, 2048, 2048);
}

// Round 3
// 477.187 us; speedup vs baseline: 1.7397x; 1.1342x over previous
//
#include <hip/hip_runtime.h>

typedef short short8 __attribute__((ext_vector_type(8)));
typedef float f32x4 __attribute__((ext_vector_type(4)));

#define MFMA_BF16 __builtin_amdgcn_mfma_f32_16x16x32_bf16

__device__ __forceinline__ unsigned short f2bf(float f) {
  unsigned int u = __float_as_uint(f);
  u += 0x7fffu + ((u >> 16) & 1u);   // round-to-nearest-even
  return (unsigned short)(u >> 16);
}
__device__ __forceinline__ float bf2f(unsigned short u) {
  return __uint_as_float(((unsigned int)u) << 16);
}

// async global->LDS, 16B per lane. LDS dest = wave-uniform base + lane*16.
typedef __attribute__((address_space(1))) const unsigned int as1_u32;
typedef __attribute__((address_space(3))) unsigned int as3_u32;
__device__ __forceinline__ void gld16(const void* g, void* l) {
  __builtin_amdgcn_global_load_lds((as1_u32*)(unsigned long long)g,
                                   (as3_u32*)(unsigned int)(unsigned long long)l,
                                   16, 0, 0);
}

// ---------------------------------------------------------------------------
// Fused f32 -> bf16 convert: 7 segments selected by blockIdx.y.
// ---------------------------------------------------------------------------
struct CvtArgs {
  const float* s[7];
  unsigned short* d[7];
  int n8[7];
};

__global__ __launch_bounds__(256) void cvtall(CvtArgs a) {
  const int seg = blockIdx.y;
  int i = blockIdx.x * 256 + threadIdx.x;
  if (i >= a.n8[seg]) return;
  const float4* s4 = (const float4*)a.s[seg];
  float4 x = s4[2 * i], y = s4[2 * i + 1];
  short8 o = {(short)f2bf(x.x), (short)f2bf(x.y), (short)f2bf(x.z), (short)f2bf(x.w),
              (short)f2bf(y.x), (short)f2bf(y.y), (short)f2bf(y.z), (short)f2bf(y.w)};
  *(short8*)&a.d[seg][(size_t)i * 8] = o;
}

// ---------------------------------------------------------------------------
// GEMM (m97 structure): C[m,n] = sum_k A[m,k]*W[n,k] + bias[n]
// A (M,K) bf16, W (N,K) bf16. 128x128 tile, BK=32, 256 thr, global_load_lds.
// grid.z selects one of up to 3 (A,W,bias,C) problem instances.
// ---------------------------------------------------------------------------
template <bool OUTBF>
__global__ __launch_bounds__(256) void gemm_bf16(
    const unsigned short* __restrict__ A0, const unsigned short* __restrict__ A1,
    const unsigned short* __restrict__ A2,
    const unsigned short* __restrict__ W0, const unsigned short* __restrict__ W1,
    const unsigned short* __restrict__ W2,
    const float* __restrict__ g0, const float* __restrict__ g1,
    const float* __restrict__ g2,
    float* __restrict__ Cf0, unsigned short* __restrict__ Cb0,
    unsigned short* __restrict__ Cb1, unsigned short* __restrict__ Cb2,
    int M, int N, int K) {
  const int z = blockIdx.z;
  const unsigned short* A = z == 0 ? A0 : (z == 1 ? A1 : A2);
  const unsigned short* W = z == 0 ? W0 : (z == 1 ? W1 : W2);
  const float* bias = z == 0 ? g0 : (z == 1 ? g1 : g2);
  unsigned short* Cb = z == 0 ? Cb0 : (z == 1 ? Cb1 : Cb2);

  __shared__ unsigned short As[128 * 32];
  __shared__ unsigned short Bs[128 * 32];
  const int t = threadIdx.x, lane = t & 63, w = t >> 6;
  const int wr = w >> 1, wc = w & 1;
  const int quad = lane >> 4, l16 = lane & 15;
  const int bm = blockIdx.y * 128, bn = blockIdx.x * 128;

  const int r0 = (w * 2 + 0) * 16 + (lane >> 2);
  const int r1 = (w * 2 + 1) * 16 + (lane >> 2);
  const size_t a0 = (size_t)(bm + r0) * K + (lane & 3) * 8;
  const size_t a1 = (size_t)(bm + r1) * K + (lane & 3) * 8;
  const size_t b0 = (size_t)(bn + r0) * K + (lane & 3) * 8;
  const size_t b1 = (size_t)(bn + r1) * K + (lane & 3) * 8;
  unsigned short* lA0 = &As[(w * 2 + 0) * 512];
  unsigned short* lA1 = &As[(w * 2 + 1) * 512];
  unsigned short* lB0 = &Bs[(w * 2 + 0) * 512];
  unsigned short* lB1 = &Bs[(w * 2 + 1) * 512];

  const f32x4 fz = {0.f, 0.f, 0.f, 0.f};
  f32x4 acc[4][4];
  for (int i = 0; i < 4; ++i)
    for (int j = 0; j < 4; ++j) acc[i][j] = fz;

  for (int k0 = 0; k0 < K; k0 += 32) {
    __syncthreads();
    gld16(A + a0 + k0, lA0);
    gld16(A + a1 + k0, lA1);
    gld16(W + b0 + k0, lB0);
    gld16(W + b1 + k0, lB1);
    __syncthreads();
    short8 af[4], bfv[4];
    for (int mt = 0; mt < 4; ++mt)
      af[mt] = *(const short8*)&As[(wr * 64 + mt * 16 + l16) * 32 + quad * 8];
    for (int nt = 0; nt < 4; ++nt)
      bfv[nt] = *(const short8*)&Bs[(wc * 64 + nt * 16 + l16) * 32 + quad * 8];
    for (int mt = 0; mt < 4; ++mt)
      for (int nt = 0; nt < 4; ++nt)
        acc[mt][nt] = MFMA_BF16(af[mt], bfv[nt], acc[mt][nt], 0, 0, 0);
  }

  for (int mt = 0; mt < 4; ++mt)
    for (int nt = 0; nt < 4; ++nt) {
      int row = bm + wr * 64 + mt * 16 + quad * 4;
      int col = bn + wc * 64 + nt * 16 + l16;
      float bc = bias[col];
      for (int r = 0; r < 4; ++r) {
        float v = acc[mt][nt][r] + bc;
        if (OUTBF) Cb[(size_t)(row + r) * N + col] = f2bf(v);
        else       Cf0[(size_t)(row + r) * N + col] = v;
      }
    }
}

// ---------------------------------------------------------------------------
// RMSNorm + rotary on Q,K (bf16 in/out, f32 math). Wave per row.
// Softmax scale (1/sqrt(d)) * log2(e) folded into Q.
// ---------------------------------------------------------------------------
__global__ __launch_bounds__(256) void rmsrope(
    const unsigned short* __restrict__ Qf, const unsigned short* __restrict__ Kf,
    const float* __restrict__ cosT, const float* __restrict__ sinT,
    unsigned short* __restrict__ Qb, unsigned short* __restrict__ Kb) {
  const int rid = blockIdx.x * 4 + (threadIdx.x >> 6);  // (b*16+h)*1024 + l
  const int lane = threadIdx.x & 63;
  const int li = rid & 1023;
  const int bh = rid >> 10;
  const int hi = bh & 15, bi = bh >> 4;
  const int src = (bi * 1024 + li) * 2048 + hi * 128;
  const int dst = rid * 128;
  const float c = cosT[li * 64 + lane];
  const float s = sinT[li * 64 + lane];

  float q1 = bf2f(Qf[src + lane]), q2 = bf2f(Qf[src + 64 + lane]);
  float ss = q1 * q1 + q2 * q2;
  for (int off = 32; off; off >>= 1) ss += __shfl_xor(ss, off, 64);
  float r = rsqrtf(ss * (1.f / 128.f) + 1e-6f);
  float qa = q1 * r, qb2 = q2 * r;
  const float qsc = 0.08838834764831845f * 1.4426950408889634f;
  Qb[dst + lane]      = f2bf((qa * c - qb2 * s) * qsc);
  Qb[dst + 64 + lane] = f2bf((qa * s + qb2 * c) * qsc);

  float k1 = bf2f(Kf[src + lane]), k2 = bf2f(Kf[src + 64 + lane]);
  float ks = k1 * k1 + k2 * k2;
  for (int off = 32; off; off >>= 1) ks += __shfl_xor(ks, off, 64);
  float rk = rsqrtf(ks * (1.f / 128.f) + 1e-6f);
  float ka = k1 * rk, kb2 = k2 * rk;
  Kb[dst + lane]      = f2bf(ka * c - kb2 * s);
  Kb[dst + 64 + lane] = f2bf(ka * s + kb2 * c);
}

// ---------------------------------------------------------------------------
// V transpose: Vf bf16 (b,l,e) -> Vt bf16 (b,h,d,l).
// ---------------------------------------------------------------------------
__global__ __launch_bounds__(256) void vtrans(
    const unsigned short* __restrict__ Vf, unsigned short* __restrict__ Vt) {
  __shared__ unsigned short Vsh[64 * 136];
  const int t = threadIdx.x;
  const int bh = blockIdx.y, l0 = blockIdx.x * 64;
  const int hi = bh & 15, bi = bh >> 4;
  {
    int row = t >> 2, c4 = t & 3;
    const unsigned short* src = &Vf[(size_t)(bi * 1024 + l0 + row) * 2048 + hi * 128];
    for (int i = 0; i < 4; ++i) {
      int chunk = c4 * 4 + i;
      *(int4*)&Vsh[row * 136 + chunk * 8] = *(const int4*)&src[chunk * 8];
    }
  }
  __syncthreads();
  {
    int d = t >> 1, half = t & 1;
    unsigned short* dst = &Vt[(size_t)bh * 131072 + (size_t)d * 1024 + l0 + half * 32];
    for (int g = 0; g < 4; ++g) {
      short8 o;
      for (int j = 0; j < 8; ++j)
        o[j] = (short)Vsh[(half * 32 + g * 8 + j) * 136 + d];
      *(short8*)&dst[g * 8] = o;
    }
  }
}

// ---------------------------------------------------------------------------
// Flash attention, causal, static softmax max, s-SPLIT + balanced pairing.
// Block = 512 threads (8 waves). Block B: bh = (B&7) + 8*((B>>3)&7) (XCD-
// local K/V reuse), jj = B>>6; pair = jj>>1, split = jj&1.
// Processes q-tiles {7-pair, pair} (128 rows each, wave owns 16 rows).
// s-tiles of 64, tile indices st ≡ split (mod 2), st < 2t+2 -> exactly 9
// tiles per block (uniform). Static max => partials are associative: block
// writes UNNORMALIZED O (bf16) to Of[split] and row sums L (f32) to Lb.
// vnfix combines. No online max, no rescale, no zero-init needed.
// ---------------------------------------------------------------------------
__global__ __launch_bounds__(512, 4) void attn(
    const unsigned short* __restrict__ Qb, const unsigned short* __restrict__ Kb,
    const unsigned short* __restrict__ Vt, unsigned short* __restrict__ Of0,
    unsigned short* __restrict__ Of1, float* __restrict__ Lb) {
  __shared__ unsigned short Kl[64 * 136];
  __shared__ unsigned short Vl[128 * 72];
  __shared__ unsigned short Pl[8][16 * 72];
  const int t = threadIdx.x, lane = t & 63, w = t >> 6;
  const int quad = lane >> 4, l16 = lane & 15;
  const int B = blockIdx.x;
  const int bh = (B & 7) + 8 * ((B >> 3) & 7);
  const int jj = B >> 6;
  const int pair = jj >> 1, split = jj & 1;
  const unsigned short* Qh = Qb + (size_t)bh * 131072;
  const unsigned short* Kh = Kb + (size_t)bh * 131072;
  const unsigned short* Vh = Vt + (size_t)bh * 131072;
  unsigned short* Oh = (split ? Of1 : Of0) + (size_t)bh * 131072;
  float* Lh = Lb + split * 65536 + bh * 1024;

  const int krow = t >> 4, kcol = (t & 15) * 8;   // K staging
  const int vdr = t >> 3, vc = (t & 7) * 8;       // V staging
  const f32x4 fz = {0.f, 0.f, 0.f, 0.f};

  for (int ti = 0; ti < 2; ++ti) {
    const int qt = ti == 0 ? 7 - pair : pair;
    const int q0 = qt * 128;

    short8 aQ[4];
    {
      int qr = q0 + w * 16 + l16;
      for (int kk = 0; kk < 4; ++kk)
        aQ[kk] = *(const short8*)&Qh[(size_t)qr * 128 + kk * 32 + quad * 8];
    }
    f32x4 oacc[8];
    for (int i = 0; i < 8; ++i) oacc[i] = fz;
    float Lr[4] = {0.f, 0.f, 0.f, 0.f};
    const int nST = 2 * qt + 2;

    for (int st = split; st < nST; st += 2) {
      const int s0 = st * 64;
      __syncthreads();
      {
        *(int4*)&Kl[krow * 136 + kcol] =
            *(const int4*)&Kh[(size_t)(s0 + krow) * 128 + kcol];
        *(int4*)&Kl[(krow + 32) * 136 + kcol] =
            *(const int4*)&Kh[(size_t)(s0 + krow + 32) * 128 + kcol];
        *(int4*)&Vl[vdr * 72 + vc] =
            *(const int4*)&Vh[(size_t)vdr * 1024 + s0 + vc];
        *(int4*)&Vl[(vdr + 64) * 72 + vc] =
            *(const int4*)&Vh[(size_t)(vdr + 64) * 1024 + s0 + vc];
      }
      __syncthreads();

      // QK^T: wave's 16 q-rows vs 64 s
      f32x4 sfr[4];
      for (int j = 0; j < 4; ++j) sfr[j] = fz;
      for (int kk = 0; kk < 4; ++kk)
        for (int ni = 0; ni < 4; ++ni) {
          short8 bK = *(const short8*)&Kl[(ni * 16 + l16) * 136 + kk * 32 + quad * 8];
          sfr[ni] = MFMA_BF16(aQ[kk], bK, sfr[ni], 0, 0, 0);
        }

      const bool diag = (s0 + 63 > q0);
      for (int r = 0; r < 4; ++r) {
        int q = q0 + w * 16 + quad * 4 + r;
        float ps = 0.f;
        for (int ni = 0; ni < 4; ++ni) {
          float sv = sfr[ni][r];
          if (diag && (s0 + ni * 16 + l16 > q)) sv = -30000.f;
          float pp = exp2f(sv - 16.5f);
          ps += pp;
          Pl[w][(quad * 4 + r) * 72 + ni * 16 + l16] = f2bf(pp);
        }
        ps += __shfl_xor(ps, 1, 64);
        ps += __shfl_xor(ps, 2, 64);
        ps += __shfl_xor(ps, 4, 64);
        ps += __shfl_xor(ps, 8, 64);
        Lr[r] += ps;
      }

      // P @ V (per-wave Pl, no barrier needed)
      for (int kk = 0; kk < 2; ++kk) {
        short8 aP = *(const short8*)&Pl[w][l16 * 72 + kk * 32 + quad * 8];
        for (int nt = 0; nt < 8; ++nt) {
          short8 bV = *(const short8*)&Vl[(nt * 16 + l16) * 72 + kk * 32 + quad * 8];
          oacc[nt] = MFMA_BF16(aP, bV, oacc[nt], 0, 0, 0);
        }
      }
    }

    // epilogue: unnormalized partials
    for (int r = 0; r < 4; ++r) {
      int q = q0 + w * 16 + quad * 4 + r;
      size_t base = (size_t)q * 128;
      for (int nt = 0; nt < 8; ++nt)
        Oh[base + nt * 16 + l16] = f2bf(oacc[nt][r]);
      if (l16 == 0) Lh[q] = Lr[r];
    }
  }
}

// ---------------------------------------------------------------------------
// Combine split partials + v-projection removal. Out bf16 (b,l,e).
// ---------------------------------------------------------------------------
__global__ __launch_bounds__(256) void vnfix(
    const unsigned short* __restrict__ Of0, const unsigned short* __restrict__ Of1,
    const float* __restrict__ Lb, const unsigned short* __restrict__ Vf,
    unsigned short* __restrict__ Op) {
  const int rid = blockIdx.x * 4 + (threadIdx.x >> 6);
  const int lane = threadIdx.x & 63;
  const int li = rid & 1023;
  const int bh = rid >> 10;
  const int hi = bh & 15, bi = bh >> 4;
  const int src = (bi * 1024 + li) * 2048 + hi * 128;
  float inv = 1.f / (Lb[rid] + Lb[65536 + rid]);
  float o1 = (bf2f(Of0[(size_t)rid * 128 + lane]) + bf2f(Of1[(size_t)rid * 128 + lane])) * inv;
  float o2 = (bf2f(Of0[(size_t)rid * 128 + 64 + lane]) + bf2f(Of1[(size_t)rid * 128 + 64 + lane])) * inv;
  float v1 = bf2f(Vf[src + lane]), v2 = bf2f(Vf[src + 64 + lane]);
  float vv = v1 * v1 + v2 * v2;
  float dd = o1 * v1 + o2 * v2;
  for (int off = 32; off; off >>= 1) {
    vv += __shfl_xor(vv, off, 64);
    dd += __shfl_xor(dd, off, 64);
  }
  float vn = fmaxf(sqrtf(vv), 1e-9f);
  float tc = dd / (vn * vn);
  Op[src + lane]      = f2bf(o1 - tc * v1);
  Op[src + 64 + lane] = f2bf(o2 - tc * v2);
}

// ---------------------------------------------------------------------------
// Workspace map (128 MB), b=4,l=1024,e=2048,h=16,d=128:
//  0-16M   Xq bf16          -> Qb (b,h,l,d) after rmsrope
//  16-32M  Xk bf16          -> Kb
//  32-48M  Xv bf16          -> Vt (b,h,d,l) after vtrans
//  48-56M  Wqb  | 56-64M Wkb    -> Opb bf16 (b,l,e) 48-64M after vnfix
//  64-72M  Wvb               -> Lb f32 (2x64x1024 = 512K) by attn
//  72-80M  Wob  (live to end)
//  80-96M  Qf bf16           -> Of0 bf16 partial by attn
//  96-112M Kf bf16           -> Of1 bf16 partial
//  112-128M Vf bf16 (live until vnfix)
// ---------------------------------------------------------------------------
extern "C" void kernel_launch(void* const* d_in, const int* in_sizes, int n_in,
                              void* d_out, int out_size, void* d_ws, size_t ws_size,
                              hipStream_t stream) {
  const float* query = (const float*)d_in[0];
  const float* key   = (const float*)d_in[1];
  const float* value = (const float*)d_in[2];
  const float* cosT  = (const float*)d_in[4];
  const float* sinT  = (const float*)d_in[5];
  const float* Wq = (const float*)d_in[6];
  const float* bq = (const float*)d_in[7];
  const float* Wk = (const float*)d_in[8];
  const float* bk = (const float*)d_in[9];
  const float* Wv = (const float*)d_in[10];
  const float* bv = (const float*)d_in[11];
  const float* Wo = (const float*)d_in[12];
  const float* bo = (const float*)d_in[13];
  float* out = (float*)d_out;

  char* ws = (char*)d_ws;
  const size_t MB = 1048576;
  unsigned short* Xq  = (unsigned short*)(ws);
  unsigned short* Xk  = (unsigned short*)(ws + 16 * MB);
  unsigned short* Xv  = (unsigned short*)(ws + 32 * MB);
  unsigned short* Wqb = (unsigned short*)(ws + 48 * MB);
  unsigned short* Wkb = (unsigned short*)(ws + 56 * MB);
  unsigned short* Wvb = (unsigned short*)(ws + 64 * MB);
  unsigned short* Wob = (unsigned short*)(ws + 72 * MB);
  unsigned short* Qf  = (unsigned short*)(ws + 80 * MB);
  unsigned short* Kf  = (unsigned short*)(ws + 96 * MB);
  unsigned short* Vf  = (unsigned short*)(ws + 112 * MB);
  unsigned short* Qbb = Xq;
  unsigned short* Kbb = Xk;
  unsigned short* Vtb = Xv;
  unsigned short* Of0 = Qf;
  unsigned short* Of1 = Kf;
  float*          Lbp = (float*)(ws + 64 * MB);
  unsigned short* Opb = (unsigned short*)(ws + 48 * MB);

  // 1. converts (one dispatch)
  CvtArgs ca;
  ca.s[0] = query; ca.d[0] = Xq;  ca.n8[0] = 1048576;
  ca.s[1] = key;   ca.d[1] = Xk;  ca.n8[1] = 1048576;
  ca.s[2] = value; ca.d[2] = Xv;  ca.n8[2] = 1048576;
  ca.s[3] = Wq;    ca.d[3] = Wqb; ca.n8[3] = 524288;
  ca.s[4] = Wk;    ca.d[4] = Wkb; ca.n8[4] = 524288;
  ca.s[5] = Wv;    ca.d[5] = Wvb; ca.n8[5] = 524288;
  ca.s[6] = Wo;    ca.d[6] = Wob; ca.n8[6] = 524288;
  cvtall<<<dim3(4096, 7), 256, 0, stream>>>(ca);

  // 2. Q,K,V projections in one dispatch (bf16 out)
  gemm_bf16<true><<<dim3(16, 32, 3), 256, 0, stream>>>(
      Xq, Xk, Xv, Wqb, Wkb, Wvb, bq, bk, bv,
      nullptr, Qf, Kf, Vf, 4096, 2048, 2048);

  // 3. rmsnorm+rope, V transpose
  rmsrope<<<16384, 256, 0, stream>>>(Qf, Kf, cosT, sinT, Qbb, Kbb);
  vtrans<<<dim3(16, 64), 256, 0, stream>>>(Vf, Vtb);

  // 4. attention (split + paired, uniform 9 tiles/block)
  attn<<<512, 512, 0, stream>>>(Qbb, Kbb, Vtb, Of0, Of1, Lbp);

  // 5. combine + v-projection removal (bf16 out)
  vnfix<<<16384, 256, 0, stream>>>(Of0, Of1, Lbp, Vf, Opb);

  // 6. output projection (f32 out)
  gemm_bf16<false><<<dim3(16, 32, 1), 256, 0, stream>>>(
      Opb, nullptr, nullptr, Wob, nullptr, nullptr, bo, nullptr, nullptr,
      out, nullptr, nullptr, nullptr, 4096, 2048, 2048);
}

// Round 4
// 473.340 us; speedup vs baseline: 1.7539x; 1.0081x over previous
//
#include <hip/hip_runtime.h>

typedef short short8 __attribute__((ext_vector_type(8)));
typedef float f32x4 __attribute__((ext_vector_type(4)));

#define MFMA_BF16 __builtin_amdgcn_mfma_f32_16x16x32_bf16

__device__ __forceinline__ unsigned short f2bf(float f) {
  unsigned int u = __float_as_uint(f);
  u += 0x7fffu + ((u >> 16) & 1u);   // round-to-nearest-even
  return (unsigned short)(u >> 16);
}
__device__ __forceinline__ float bf2f(unsigned short u) {
  return __uint_as_float(((unsigned int)u) << 16);
}

// async global->LDS, 16B per lane. LDS dest = wave-uniform base + lane*16.
typedef __attribute__((address_space(1))) const unsigned int as1_u32;
typedef __attribute__((address_space(3))) unsigned int as3_u32;
__device__ __forceinline__ void gld16(const void* g, void* l) {
  __builtin_amdgcn_global_load_lds((as1_u32*)(unsigned long long)g,
                                   (as3_u32*)(unsigned int)(unsigned long long)l,
                                   16, 0, 0);
}

// ---------------------------------------------------------------------------
// Fused f32 -> bf16 convert: 7 segments selected by blockIdx.y.
// ---------------------------------------------------------------------------
struct CvtArgs {
  const float* s[7];
  unsigned short* d[7];
  int n8[7];
};

__global__ __launch_bounds__(256) void cvtall(CvtArgs a) {
  const int seg = blockIdx.y;
  int i = blockIdx.x * 256 + threadIdx.x;
  if (i >= a.n8[seg]) return;
  const float4* s4 = (const float4*)a.s[seg];
  float4 x = s4[2 * i], y = s4[2 * i + 1];
  short8 o = {(short)f2bf(x.x), (short)f2bf(x.y), (short)f2bf(x.z), (short)f2bf(x.w),
              (short)f2bf(y.x), (short)f2bf(y.y), (short)f2bf(y.z), (short)f2bf(y.w)};
  *(short8*)&a.d[seg][(size_t)i * 8] = o;
}

// ---------------------------------------------------------------------------
// GEMM: C[m,n] = sum_k A[m,k]*W[n,k] + bias[n].  A (M,K) bf16, W (N,K) bf16.
// 128x128 tile, BK=64 (32 MFMA per barrier), 256 thr, global_load_lds w=16.
// 1-D grid, XCD swizzle: xcd=B&7 owns M-band y in [xcd*4,xcd*4+4), walks
// 4x4 (x,y) super-tiles -> ~2MB A + ~2MB W working set per XCD L2.
// NZ problem instances (z dim folded into grid).
// M=4096, N=2048, K=2048 fixed by swizzle (16 x-tiles, 32 y-tiles).
// ---------------------------------------------------------------------------
struct GemmArgs {
  const unsigned short* A[3];
  const unsigned short* W[3];
  const float* bias[3];
  unsigned short* Cb[3];
  float* Cf;
};

template <bool OUTBF, int NZ>
__global__ __launch_bounds__(256) void gemm_bf16(GemmArgs g) {
  const int B = blockIdx.x;
  const int xcd = B & 7;
  const int i = B >> 3;           // 0..NZ*64-1
  const int z = i >> 6;
  const int r = i & 63;
  const int xb = r >> 4, inner = r & 15;
  const int bn = (xb * 4 + (inner & 3)) * 128;
  const int bm = (xcd * 4 + (inner >> 2)) * 128;
  const int K = 2048, N = 2048;

  const unsigned short* A = g.A[z];
  const unsigned short* W = g.W[z];
  const float* bias = g.bias[z];
  unsigned short* Cb = g.Cb[z];

  __shared__ unsigned short As[128 * 64];
  __shared__ unsigned short Bs[128 * 64];
  const int t = threadIdx.x, lane = t & 63, w = t >> 6;
  const int wr = w >> 1, wc = w & 1;
  const int quad = lane >> 4, l16 = lane & 15;

  // staging: wave w, instr j in 0..3 covers rows (w*4+j)*8 + (lane>>3),
  // k-chunk (lane&7)*8. LDS dest region = 1KB contiguous, lane-ordered.
  const int srow = lane >> 3;
  const int sk = (lane & 7) * 8;
  size_t ga[4], gb[4];
  unsigned short *la[4], *lb[4];
  for (int j = 0; j < 4; ++j) {
    int rr = (w * 4 + j) * 8 + srow;
    ga[j] = (size_t)(bm + rr) * K + sk;
    gb[j] = (size_t)(bn + rr) * K + sk;
    la[j] = &As[(w * 4 + j) * 512];
    lb[j] = &Bs[(w * 4 + j) * 512];
  }

  const f32x4 fz = {0.f, 0.f, 0.f, 0.f};
  f32x4 acc[4][4];
  for (int a = 0; a < 4; ++a)
    for (int b = 0; b < 4; ++b) acc[a][b] = fz;

  for (int k0 = 0; k0 < K; k0 += 64) {
    __syncthreads();
    for (int j = 0; j < 4; ++j) {
      gld16(A + ga[j] + k0, la[j]);
      gld16(W + gb[j] + k0, lb[j]);
    }
    __syncthreads();
    for (int kk = 0; kk < 2; ++kk) {
      short8 af[4], bfv[4];
      for (int mt = 0; mt < 4; ++mt)
        af[mt] = *(const short8*)&As[(wr * 64 + mt * 16 + l16) * 64 + kk * 32 + quad * 8];
      for (int nt = 0; nt < 4; ++nt)
        bfv[nt] = *(const short8*)&Bs[(wc * 64 + nt * 16 + l16) * 64 + kk * 32 + quad * 8];
      for (int mt = 0; mt < 4; ++mt)
        for (int nt = 0; nt < 4; ++nt)
          acc[mt][nt] = MFMA_BF16(af[mt], bfv[nt], acc[mt][nt], 0, 0, 0);
    }
  }

  for (int mt = 0; mt < 4; ++mt)
    for (int nt = 0; nt < 4; ++nt) {
      int row = bm + wr * 64 + mt * 16 + quad * 4;
      int col = bn + wc * 64 + nt * 16 + l16;
      float bc = bias[col];
      for (int r2 = 0; r2 < 4; ++r2) {
        float v = acc[mt][nt][r2] + bc;
        if (OUTBF) Cb[(size_t)(row + r2) * N + col] = f2bf(v);
        else       g.Cf[(size_t)(row + r2) * N + col] = v;
      }
    }
}

// ---------------------------------------------------------------------------
// Fused RMSNorm+rotary (Q,K) and V transpose.
// Blocks [0,16384): rmsrope, one wave per (b,h,l) row.
// Blocks [16384,17408): vtrans, Vf bf16 (b,l,e) -> Vt bf16 (b,h,d,l).
// ---------------------------------------------------------------------------
__global__ __launch_bounds__(256) void rmsvt(
    const unsigned short* __restrict__ Qf, const unsigned short* __restrict__ Kf,
    const unsigned short* __restrict__ Vf,
    const float* __restrict__ cosT, const float* __restrict__ sinT,
    unsigned short* __restrict__ Qb, unsigned short* __restrict__ Kb,
    unsigned short* __restrict__ Vt) {
  __shared__ unsigned short Vsh[64 * 136];
  if (blockIdx.x < 16384) {
    const int rid = blockIdx.x * 4 + (threadIdx.x >> 6);
    const int lane = threadIdx.x & 63;
    const int li = rid & 1023;
    const int bh = rid >> 10;
    const int hi = bh & 15, bi = bh >> 4;
    const int src = (bi * 1024 + li) * 2048 + hi * 128;
    const int dst = rid * 128;
    const float c = cosT[li * 64 + lane];
    const float s = sinT[li * 64 + lane];

    float q1 = bf2f(Qf[src + lane]), q2 = bf2f(Qf[src + 64 + lane]);
    float ss = q1 * q1 + q2 * q2;
    for (int off = 32; off; off >>= 1) ss += __shfl_xor(ss, off, 64);
    float r = rsqrtf(ss * (1.f / 128.f) + 1e-6f);
    float qa = q1 * r, qb2 = q2 * r;
    const float qsc = 0.08838834764831845f * 1.4426950408889634f;
    Qb[dst + lane]      = f2bf((qa * c - qb2 * s) * qsc);
    Qb[dst + 64 + lane] = f2bf((qa * s + qb2 * c) * qsc);

    float k1 = bf2f(Kf[src + lane]), k2 = bf2f(Kf[src + 64 + lane]);
    float ks = k1 * k1 + k2 * k2;
    for (int off = 32; off; off >>= 1) ks += __shfl_xor(ks, off, 64);
    float rk = rsqrtf(ks * (1.f / 128.f) + 1e-6f);
    float ka = k1 * rk, kb2 = k2 * rk;
    Kb[dst + lane]      = f2bf(ka * c - kb2 * s);
    Kb[dst + 64 + lane] = f2bf(ka * s + kb2 * c);
  } else {
    const int bid = blockIdx.x - 16384;
    const int t = threadIdx.x;
    const int bh = bid >> 4, l0 = (bid & 15) * 64;
    const int hi = bh & 15, bi = bh >> 4;
    {
      int row = t >> 2, c4 = t & 3;
      const unsigned short* src = &Vf[(size_t)(bi * 1024 + l0 + row) * 2048 + hi * 128];
      for (int i = 0; i < 4; ++i) {
        int chunk = c4 * 4 + i;
        *(int4*)&Vsh[row * 136 + chunk * 8] = *(const int4*)&src[chunk * 8];
      }
    }
    __syncthreads();
    {
      int d = t >> 1, half = t & 1;
      unsigned short* dst = &Vt[(size_t)bh * 131072 + (size_t)d * 1024 + l0 + half * 32];
      for (int g = 0; g < 4; ++g) {
        short8 o;
        for (int j = 0; j < 8; ++j)
          o[j] = (short)Vsh[(half * 32 + g * 8 + j) * 136 + d];
        *(short8*)&dst[g * 8] = o;
      }
    }
  }
}

// ---------------------------------------------------------------------------
// Flash attention, causal, static softmax max, s-SPLIT + balanced pairing.
// Block = 512 threads (8 waves). Block B: bh = (B&7) + 8*((B>>3)&7) (XCD-
// local K/V), jj = B>>6; pair = jj>>1, split = jj&1. q-tiles {7-pair, pair},
// s-tiles of 64 with st ≡ split (mod 2) -> exactly 9 tiles/block.
// Static max => partials associative: unnormalized O (bf16) + L (f32).
// ---------------------------------------------------------------------------
__global__ __launch_bounds__(512, 4) void attn(
    const unsigned short* __restrict__ Qb, const unsigned short* __restrict__ Kb,
    const unsigned short* __restrict__ Vt, unsigned short* __restrict__ Of0,
    unsigned short* __restrict__ Of1, float* __restrict__ Lb) {
  __shared__ unsigned short Kl[64 * 136];
  __shared__ unsigned short Vl[128 * 72];
  __shared__ unsigned short Pl[8][16 * 72];
  const int t = threadIdx.x, lane = t & 63, w = t >> 6;
  const int quad = lane >> 4, l16 = lane & 15;
  const int B = blockIdx.x;
  const int bh = (B & 7) + 8 * ((B >> 3) & 7);
  const int jj = B >> 6;
  const int pair = jj >> 1, split = jj & 1;
  const unsigned short* Qh = Qb + (size_t)bh * 131072;
  const unsigned short* Kh = Kb + (size_t)bh * 131072;
  const unsigned short* Vh = Vt + (size_t)bh * 131072;
  unsigned short* Oh = (split ? Of1 : Of0) + (size_t)bh * 131072;
  float* Lh = Lb + split * 65536 + bh * 1024;

  const int krow = t >> 4, kcol = (t & 15) * 8;
  const int vdr = t >> 3, vc = (t & 7) * 8;
  const f32x4 fz = {0.f, 0.f, 0.f, 0.f};

  for (int ti = 0; ti < 2; ++ti) {
    const int qt = ti == 0 ? 7 - pair : pair;
    const int q0 = qt * 128;

    short8 aQ[4];
    {
      int qr = q0 + w * 16 + l16;
      for (int kk = 0; kk < 4; ++kk)
        aQ[kk] = *(const short8*)&Qh[(size_t)qr * 128 + kk * 32 + quad * 8];
    }
    f32x4 oacc[8];
    for (int i = 0; i < 8; ++i) oacc[i] = fz;
    float Lr[4] = {0.f, 0.f, 0.f, 0.f};
    const int nST = 2 * qt + 2;

    for (int st = split; st < nST; st += 2) {
      const int s0 = st * 64;
      __syncthreads();
      {
        *(int4*)&Kl[krow * 136 + kcol] =
            *(const int4*)&Kh[(size_t)(s0 + krow) * 128 + kcol];
        *(int4*)&Kl[(krow + 32) * 136 + kcol] =
            *(const int4*)&Kh[(size_t)(s0 + krow + 32) * 128 + kcol];
        *(int4*)&Vl[vdr * 72 + vc] =
            *(const int4*)&Vh[(size_t)vdr * 1024 + s0 + vc];
        *(int4*)&Vl[(vdr + 64) * 72 + vc] =
            *(const int4*)&Vh[(size_t)(vdr + 64) * 1024 + s0 + vc];
      }
      __syncthreads();

      f32x4 sfr[4];
      for (int j = 0; j < 4; ++j) sfr[j] = fz;
      for (int kk = 0; kk < 4; ++kk)
        for (int ni = 0; ni < 4; ++ni) {
          short8 bK = *(const short8*)&Kl[(ni * 16 + l16) * 136 + kk * 32 + quad * 8];
          sfr[ni] = MFMA_BF16(aQ[kk], bK, sfr[ni], 0, 0, 0);
        }

      const bool diag = (s0 + 63 > q0);
      for (int r = 0; r < 4; ++r) {
        int q = q0 + w * 16 + quad * 4 + r;
        float ps = 0.f;
        for (int ni = 0; ni < 4; ++ni) {
          float sv = sfr[ni][r];
          if (diag && (s0 + ni * 16 + l16 > q)) sv = -30000.f;
          float pp = exp2f(sv - 16.5f);
          ps += pp;
          Pl[w][(quad * 4 + r) * 72 + ni * 16 + l16] = f2bf(pp);
        }
        ps += __shfl_xor(ps, 1, 64);
        ps += __shfl_xor(ps, 2, 64);
        ps += __shfl_xor(ps, 4, 64);
        ps += __shfl_xor(ps, 8, 64);
        Lr[r] += ps;
      }

      for (int kk = 0; kk < 2; ++kk) {
        short8 aP = *(const short8*)&Pl[w][l16 * 72 + kk * 32 + quad * 8];
        for (int nt = 0; nt < 8; ++nt) {
          short8 bV = *(const short8*)&Vl[(nt * 16 + l16) * 72 + kk * 32 + quad * 8];
          oacc[nt] = MFMA_BF16(aP, bV, oacc[nt], 0, 0, 0);
        }
      }
    }

    for (int r = 0; r < 4; ++r) {
      int q = q0 + w * 16 + quad * 4 + r;
      size_t base = (size_t)q * 128;
      for (int nt = 0; nt < 8; ++nt)
        Oh[base + nt * 16 + l16] = f2bf(oacc[nt][r]);
      if (l16 == 0) Lh[q] = Lr[r];
    }
  }
}

// ---------------------------------------------------------------------------
// Combine split partials + v-projection removal. Out bf16 (b,l,e).
// ---------------------------------------------------------------------------
__global__ __launch_bounds__(256) void vnfix(
    const unsigned short* __restrict__ Of0, const unsigned short* __restrict__ Of1,
    const float* __restrict__ Lb, const unsigned short* __restrict__ Vf,
    unsigned short* __restrict__ Op) {
  const int rid = blockIdx.x * 4 + (threadIdx.x >> 6);
  const int lane = threadIdx.x & 63;
  const int li = rid & 1023;
  const int bh = rid >> 10;
  const int hi = bh & 15, bi = bh >> 4;
  const int src = (bi * 1024 + li) * 2048 + hi * 128;
  float inv = 1.f / (Lb[rid] + Lb[65536 + rid]);
  float o1 = (bf2f(Of0[(size_t)rid * 128 + lane]) + bf2f(Of1[(size_t)rid * 128 + lane])) * inv;
  float o2 = (bf2f(Of0[(size_t)rid * 128 + 64 + lane]) + bf2f(Of1[(size_t)rid * 128 + 64 + lane])) * inv;
  float v1 = bf2f(Vf[src + lane]), v2 = bf2f(Vf[src + 64 + lane]);
  float vv = v1 * v1 + v2 * v2;
  float dd = o1 * v1 + o2 * v2;
  for (int off = 32; off; off >>= 1) {
    vv += __shfl_xor(vv, off, 64);
    dd += __shfl_xor(dd, off, 64);
  }
  float vn = fmaxf(sqrtf(vv), 1e-9f);
  float tc = dd / (vn * vn);
  Op[src + lane]      = f2bf(o1 - tc * v1);
  Op[src + 64 + lane] = f2bf(o2 - tc * v2);
}

// ---------------------------------------------------------------------------
// Workspace map (128 MB), b=4,l=1024,e=2048,h=16,d=128:
//  0-16M   Xq bf16          -> Qb (b,h,l,d) after rmsvt
//  16-32M  Xk bf16          -> Kb
//  32-48M  Xv bf16          -> Vt (b,h,d,l) after rmsvt
//  48-56M  Wqb | 56-64M Wkb -> Opb bf16 (b,l,e) 48-64M after vnfix
//  64-72M  Wvb              -> Lb f32 (512K) by attn
//  72-80M  Wob (live to end)
//  80-96M  Qf bf16          -> Of0 bf16 partial
//  96-112M Kf bf16          -> Of1 bf16 partial
//  112-128M Vf bf16 (live until vnfix)
// ---------------------------------------------------------------------------
extern "C" void kernel_launch(void* const* d_in, const int* in_sizes, int n_in,
                              void* d_out, int out_size, void* d_ws, size_t ws_size,
                              hipStream_t stream) {
  const float* query = (const float*)d_in[0];
  const float* key   = (const float*)d_in[1];
  const float* value = (const float*)d_in[2];
  const float* cosT  = (const float*)d_in[4];
  const float* sinT  = (const float*)d_in[5];
  const float* Wq = (const float*)d_in[6];
  const float* bq = (const float*)d_in[7];
  const float* Wk = (const float*)d_in[8];
  const float* bk = (const float*)d_in[9];
  const float* Wv = (const float*)d_in[10];
  const float* bv = (const float*)d_in[11];
  const float* Wo = (const float*)d_in[12];
  const float* bo = (const float*)d_in[13];
  float* out = (float*)d_out;

  char* ws = (char*)d_ws;
  const size_t MB = 1048576;
  unsigned short* Xq  = (unsigned short*)(ws);
  unsigned short* Xk  = (unsigned short*)(ws + 16 * MB);
  unsigned short* Xv  = (unsigned short*)(ws + 32 * MB);
  unsigned short* Wqb = (unsigned short*)(ws + 48 * MB);
  unsigned short* Wkb = (unsigned short*)(ws + 56 * MB);
  unsigned short* Wvb = (unsigned short*)(ws + 64 * MB);
  unsigned short* Wob = (unsigned short*)(ws + 72 * MB);
  unsigned short* Qf  = (unsigned short*)(ws + 80 * MB);
  unsigned short* Kf  = (unsigned short*)(ws + 96 * MB);
  unsigned short* Vf  = (unsigned short*)(ws + 112 * MB);
  unsigned short* Qbb = Xq;
  unsigned short* Kbb = Xk;
  unsigned short* Vtb = Xv;
  unsigned short* Of0 = Qf;
  unsigned short* Of1 = Kf;
  float*          Lbp = (float*)(ws + 64 * MB);
  unsigned short* Opb = (unsigned short*)(ws + 48 * MB);

  // 1. converts
  CvtArgs ca;
  ca.s[0] = query; ca.d[0] = Xq;  ca.n8[0] = 1048576;
  ca.s[1] = key;   ca.d[1] = Xk;  ca.n8[1] = 1048576;
  ca.s[2] = value; ca.d[2] = Xv;  ca.n8[2] = 1048576;
  ca.s[3] = Wq;    ca.d[3] = Wqb; ca.n8[3] = 524288;
  ca.s[4] = Wk;    ca.d[4] = Wkb; ca.n8[4] = 524288;
  ca.s[5] = Wv;    ca.d[5] = Wvb; ca.n8[5] = 524288;
  ca.s[6] = Wo;    ca.d[6] = Wob; ca.n8[6] = 524288;
  cvtall<<<dim3(4096, 7), 256, 0, stream>>>(ca);

  // 2. Q,K,V projections (one dispatch, BK=64, XCD swizzle)
  GemmArgs gp;
  gp.A[0] = Xq;  gp.A[1] = Xk;  gp.A[2] = Xv;
  gp.W[0] = Wqb; gp.W[1] = Wkb; gp.W[2] = Wvb;
  gp.bias[0] = bq; gp.bias[1] = bk; gp.bias[2] = bv;
  gp.Cb[0] = Qf; gp.Cb[1] = Kf; gp.Cb[2] = Vf;
  gp.Cf = nullptr;
  gemm_bf16<true, 3><<<1536, 256, 0, stream>>>(gp);

  // 3. rmsnorm+rope + V transpose (one dispatch)
  rmsvt<<<17408, 256, 0, stream>>>(Qf, Kf, Vf, cosT, sinT, Qbb, Kbb, Vtb);

  // 4. attention
  attn<<<512, 512, 0, stream>>>(Qbb, Kbb, Vtb, Of0, Of1, Lbp);

  // 5. combine + v-projection removal
  vnfix<<<16384, 256, 0, stream>>>(Of0, Of1, Lbp, Vf, Opb);

  // 6. output projection
  GemmArgs go;
  go.A[0] = Opb; go.A[1] = nullptr; go.A[2] = nullptr;
  go.W[0] = Wob; go.W[1] = nullptr; go.W[2] = nullptr;
  go.bias[0] = bo; go.bias[1] = nullptr; go.bias[2] = nullptr;
  go.Cb[0] = nullptr; go.Cb[1] = nullptr; go.Cb[2] = nullptr;
  go.Cf = out;
  gemm_bf16<false, 1><<<512, 256, 0, stream>>>(go);
}